// Round 1
// baseline (662.777 us; speedup 1.0000x reference)
//
#include <hip/hip_runtime.h>
#include <math.h>

#define NN 4
#define CCH 128
#define HH 96
#define WW 96
#define GG 4
#define GC 32
#define PP 9
#define NPIX (NN*HH*WW)

// ---------------- Kernel A: input projection (NCHW x -> NHWC xp = x@w_in + b_in)
__global__ __launch_bounds__(128) void k_proj(const float* __restrict__ x,
    const float* __restrict__ w_in, const float* __restrict__ b_in,
    float* __restrict__ xp) {
  __shared__ float xs[CCH];
  int pix = blockIdx.x;
  int w = pix % WW; int h = (pix / WW) % HH; int n = pix / (WW*HH);
  int c = threadIdx.x;
  xs[c] = x[(((size_t)n*CCH + c)*HH + h)*WW + w];
  __syncthreads();
  float s = b_in[c];
  #pragma unroll 8
  for (int k = 0; k < CCH; ++k) s = fmaf(xs[k], w_in[k*CCH + c], s);
  xp[(size_t)pix*CCH + c] = s;
}

// ---------------- Kernel B: depthwise conv 3x3 + bias + LayerNorm + exact GELU -> x1 (NHWC)
__global__ __launch_bounds__(128) void k_dwln(const float* __restrict__ x,
    const float* __restrict__ dw_w, const float* __restrict__ dw_b,
    const float* __restrict__ ln_g, const float* __restrict__ ln_b,
    float* __restrict__ x1) {
  __shared__ float red[CCH];
  int pix = blockIdx.x;
  int w = pix % WW; int h = (pix / WW) % HH; int n = pix / (WW*HH);
  int c = threadIdx.x;
  const float* xc = x + ((size_t)n*CCH + c)*HH*WW;
  float s = 0.f;
  #pragma unroll
  for (int kh = 0; kh < 3; ++kh) {
    int yy = h - 1 + kh;
    if (yy < 0 || yy >= HH) continue;
    #pragma unroll
    for (int kw = 0; kw < 3; ++kw) {
      int xx = w - 1 + kw;
      if (xx < 0 || xx >= WW) continue;
      s = fmaf(xc[yy*WW + xx], dw_w[(c*3 + kh)*3 + kw], s);
    }
  }
  s += dw_b[c];
  // LayerNorm over channels (128)
  red[c] = s; __syncthreads();
  #pragma unroll
  for (int off = 64; off >= 1; off >>= 1) {
    if (c < off) red[c] += red[c + off];
    __syncthreads();
  }
  float mean = red[0] * (1.f/128.f);
  __syncthreads();
  float d = s - mean;
  red[c] = d * d; __syncthreads();
  #pragma unroll
  for (int off = 64; off >= 1; off >>= 1) {
    if (c < off) red[c] += red[c + off];
    __syncthreads();
  }
  float var = red[0] * (1.f/128.f);
  float v = d * rsqrtf(var + 1e-5f) * ln_g[c] + ln_b[c];
  // exact GELU: 0.5*v*(1+erf(v/sqrt(2)))
  float g = 0.5f * v * (1.f + erff(v * 0.70710678f));
  x1[(size_t)pix*CCH + c] = g;
}

// ---------------- Kernel C: offset & mask heads + per-group softmax
__global__ __launch_bounds__(128) void k_offmask(const float* __restrict__ x1,
    const float* __restrict__ w_off, const float* __restrict__ b_off,
    const float* __restrict__ w_mask, const float* __restrict__ b_mask,
    float* __restrict__ off, float* __restrict__ mask) {
  __shared__ float xs[CCH];
  __shared__ float ml[GG*PP];
  int pix = blockIdx.x;
  int t = threadIdx.x;
  xs[t] = x1[(size_t)pix*CCH + t];
  __syncthreads();
  if (t < GG*PP*2) {               // 72 offset outputs
    float s = b_off[t];
    #pragma unroll 8
    for (int k = 0; k < CCH; ++k) s = fmaf(xs[k], w_off[k*(GG*PP*2) + t], s);
    off[(size_t)pix*(GG*PP*2) + t] = s;
  } else if (t < GG*PP*2 + GG*PP) { // 36 mask logits
    int j = t - GG*PP*2;
    float s = b_mask[j];
    #pragma unroll 8
    for (int k = 0; k < CCH; ++k) s = fmaf(xs[k], w_mask[k*(GG*PP) + j], s);
    ml[j] = s;
  }
  __syncthreads();
  if (t >= GG*PP*2 && t < GG*PP*2 + GG*PP) {
    int j = t - GG*PP*2;
    int g = j / PP;
    float mx = -1e30f;
    #pragma unroll
    for (int q = 0; q < PP; ++q) mx = fmaxf(mx, ml[g*PP + q]);
    float sum = 0.f;
    #pragma unroll
    for (int q = 0; q < PP; ++q) sum += expf(ml[g*PP + q] - mx);
    mask[(size_t)pix*(GG*PP) + j] = expf(ml[j] - mx) / sum;
  }
}

// ---------------- Kernel D: DCNv3 bilinear sampling core
__global__ __launch_bounds__(128) void k_dcn(const float* __restrict__ xp,
    const float* __restrict__ off, const float* __restrict__ mask,
    float* __restrict__ dcn) {
  __shared__ float offs[GG*PP*2];
  __shared__ float ms[GG*PP];
  int pix = blockIdx.x;
  int w = pix % WW; int h = (pix / WW) % HH; int n = pix / (WW*HH);
  int t = threadIdx.x;
  if (t < GG*PP*2) offs[t] = off[(size_t)pix*(GG*PP*2) + t];
  else if (t < GG*PP*2 + GG*PP) ms[t - GG*PP*2] = mask[(size_t)pix*(GG*PP) + (t - GG*PP*2)];
  __syncthreads();
  int g = t >> 5, cc = t & 31;
  const float* base = xp + (size_t)n*HH*WW*CCH + g*GC + cc;
  float acc = 0.f;
  #pragma unroll
  for (int p = 0; p < PP; ++p) {
    float offx = offs[(g*PP + p)*2 + 0];
    float offy = offs[(g*PP + p)*2 + 1];
    // sampling position in padded frame, denormalized:
    // ix = w + 1 + lin[p/3] + offx ; iy = h + 1 + lin[p%3] + offy
    float ix = (float)w + 1.0f + (float)(p / 3 - 1) + offx;
    float iy = (float)h + 1.0f + (float)(p % 3 - 1) + offy;
    float x0f = floorf(ix), y0f = floorf(iy);
    float wx1 = ix - x0f, wx0 = 1.f - wx1;
    float wy1 = iy - y0f, wy0 = 1.f - wy1;
    int x0i = (int)x0f, y0i = (int)y0f;
    // padded coord -> original coord: subtract PAD(=1)
    int ox0 = x0i - 1, oy0 = y0i - 1;
    int ox1 = x0i,     oy1 = y0i;      // (x0i+1)-1
    float v = 0.f;
    if (oy0 >= 0 && oy0 < HH) {
      if (ox0 >= 0 && ox0 < WW) v = fmaf(wy0*wx0, base[((size_t)oy0*WW + ox0)*CCH], v);
      if (ox1 >= 0 && ox1 < WW) v = fmaf(wy0*wx1, base[((size_t)oy0*WW + ox1)*CCH], v);
    }
    if (oy1 >= 0 && oy1 < HH) {
      if (ox0 >= 0 && ox0 < WW) v = fmaf(wy1*wx0, base[((size_t)oy1*WW + ox0)*CCH], v);
      if (ox1 >= 0 && ox1 < WW) v = fmaf(wy1*wx1, base[((size_t)oy1*WW + ox1)*CCH], v);
    }
    acc = fmaf(ms[g*PP + p], v, acc);
  }
  dcn[(size_t)pix*CCH + t] = acc;
}

// ---------------- Kernel E: output projection + BatchNorm(eval) + SiLU -> NCHW
__global__ __launch_bounds__(128) void k_outproj(const float* __restrict__ dcn,
    const float* __restrict__ w_out, const float* __restrict__ b_out,
    const float* __restrict__ bn_g, const float* __restrict__ bn_b,
    const float* __restrict__ bn_mean, const float* __restrict__ bn_var,
    float* __restrict__ y) {
  __shared__ float xs[CCH];
  int pix = blockIdx.x;
  int w = pix % WW; int h = (pix / WW) % HH; int n = pix / (WW*HH);
  int c = threadIdx.x;
  xs[c] = dcn[(size_t)pix*CCH + c];
  __syncthreads();
  float s = b_out[c];
  #pragma unroll 8
  for (int k = 0; k < CCH; ++k) s = fmaf(xs[k], w_out[k*CCH + c], s);
  float inv = rsqrtf(bn_var[c] + 1e-5f);
  float v = (s - bn_mean[c]) * (inv * bn_g[c]) + bn_b[c];
  float sig = 1.f / (1.f + expf(-v));
  y[(((size_t)n*CCH + c)*HH + h)*WW + w] = v * sig;
}

extern "C" void kernel_launch(void* const* d_in, const int* in_sizes, int n_in,
                              void* d_out, int out_size, void* d_ws, size_t ws_size,
                              hipStream_t stream) {
  const float* x       = (const float*)d_in[0];
  const float* dw_w    = (const float*)d_in[1];
  const float* dw_b    = (const float*)d_in[2];
  const float* ln_g    = (const float*)d_in[3];
  const float* ln_b    = (const float*)d_in[4];
  const float* w_off   = (const float*)d_in[5];
  const float* b_off   = (const float*)d_in[6];
  const float* w_mask  = (const float*)d_in[7];
  const float* b_mask  = (const float*)d_in[8];
  const float* w_in    = (const float*)d_in[9];
  const float* b_in    = (const float*)d_in[10];
  const float* w_out   = (const float*)d_in[11];
  const float* b_out   = (const float*)d_in[12];
  const float* bn_g    = (const float*)d_in[13];
  const float* bn_b    = (const float*)d_in[14];
  const float* bn_mean = (const float*)d_in[15];
  const float* bn_var  = (const float*)d_in[16];
  float* y = (float*)d_out;

  float* xp   = (float*)d_ws;                    // NPIX*128
  float* x1   = xp   + (size_t)NPIX*CCH;         // NPIX*128
  float* offb = x1   + (size_t)NPIX*CCH;         // NPIX*72
  float* mb   = offb + (size_t)NPIX*(GG*PP*2);   // NPIX*36
  float* dcn  = mb   + (size_t)NPIX*(GG*PP);     // NPIX*128

  dim3 grid(NPIX), block(CCH);
  k_proj<<<grid, block, 0, stream>>>(x, w_in, b_in, xp);
  k_dwln<<<grid, block, 0, stream>>>(x, dw_w, dw_b, ln_g, ln_b, x1);
  k_offmask<<<grid, block, 0, stream>>>(x1, w_off, b_off, w_mask, b_mask, offb, mb);
  k_dcn<<<grid, block, 0, stream>>>(xp, offb, mb, dcn);
  k_outproj<<<grid, block, 0, stream>>>(dcn, w_out, b_out, bn_g, bn_b, bn_mean, bn_var, y);
}

// Round 2
// 372.000 us; speedup vs baseline: 1.7817x; 1.7817x over previous
//
#include <hip/hip_runtime.h>
#include <math.h>

#define NN 4
#define CCH 128
#define HH 96
#define WW 96
#define SS (HH*WW)          // 9216 pixels per image
#define GG 4
#define GC 32
#define PP 9
#define NPIX (NN*HH*WW)     // 36864

// ---------------- Transpose in: x NCHW -> xT NHWC (per-n (C,S) -> (S,C))
__global__ __launch_bounds__(256) void k_tr_in(const float* __restrict__ x,
                                               float* __restrict__ xT) {
  __shared__ float tile[32][33];
  int n = blockIdx.z;
  int cs = blockIdx.y * 32;     // channel tile start
  int ps = blockIdx.x * 32;     // pixel tile start
  int tx = threadIdx.x;         // 0..31
  int ty = threadIdx.y;         // 0..7
  const float* src = x + ((size_t)n*CCH)*SS;
  #pragma unroll
  for (int i = 0; i < 4; ++i) {
    int r = ty + i*8;
    tile[r][tx] = src[(size_t)(cs + r)*SS + ps + tx];
  }
  __syncthreads();
  float* dst = xT + (size_t)n*SS*CCH;
  #pragma unroll
  for (int i = 0; i < 4; ++i) {
    int r = ty + i*8;
    dst[(size_t)(ps + r)*CCH + cs + tx] = tile[tx][r];
  }
}

// ---------------- Transpose out + BN(eval) + SiLU: o NHWC -> y NCHW
__global__ __launch_bounds__(256) void k_tr_out(const float* __restrict__ o,
    const float* __restrict__ bn_g, const float* __restrict__ bn_b,
    const float* __restrict__ bn_mean, const float* __restrict__ bn_var,
    float* __restrict__ y) {
  __shared__ float tile[32][33];
  int n = blockIdx.z;
  int cs = blockIdx.y * 32;
  int ps = blockIdx.x * 32;
  int tx = threadIdx.x;
  int ty = threadIdx.y;
  const float* src = o + (size_t)n*SS*CCH;
  int c = cs + tx;
  float inv = rsqrtf(bn_var[c] + 1e-5f);
  float sc = inv * bn_g[c];
  float sh = bn_b[c] - bn_mean[c] * sc;
  #pragma unroll
  for (int i = 0; i < 4; ++i) {
    int r = ty + i*8;                       // pixel sub-index
    float v = src[(size_t)(ps + r)*CCH + c] * sc + sh;
    float sig = 1.f / (1.f + __expf(-v));
    tile[r][tx] = v * sig;                  // tile[pixel][channel]
  }
  __syncthreads();
  float* dst = y + ((size_t)n*CCH)*SS;
  #pragma unroll
  for (int i = 0; i < 4; ++i) {
    int r = ty + i*8;                       // channel sub-index
    dst[(size_t)(cs + r)*SS + ps + tx] = tile[tx][r];
  }
}

// ---------------- Kernel A: input projection xp = xT @ w_in + b_in (4 px/block)
__global__ __launch_bounds__(128) void k_proj4(const float* __restrict__ xT,
    const float* __restrict__ w_in, const float* __restrict__ b_in,
    float* __restrict__ xp) {
  __shared__ float xs[4][CCH];
  int p0 = blockIdx.x * 4;
  int t = threadIdx.x;
  ((float4*)xs)[t] = ((const float4*)(xT + (size_t)p0*CCH))[t];
  __syncthreads();
  int c = t;
  float a0 = b_in[c], a1 = a0, a2 = a0, a3 = a0;
  #pragma unroll 4
  for (int k = 0; k < CCH; ++k) {
    float wv = w_in[k*CCH + c];
    a0 = fmaf(xs[0][k], wv, a0);
    a1 = fmaf(xs[1][k], wv, a1);
    a2 = fmaf(xs[2][k], wv, a2);
    a3 = fmaf(xs[3][k], wv, a3);
  }
  xp[(size_t)(p0+0)*CCH + c] = a0;
  xp[(size_t)(p0+1)*CCH + c] = a1;
  xp[(size_t)(p0+2)*CCH + c] = a2;
  xp[(size_t)(p0+3)*CCH + c] = a3;
}

// ---------------- Kernel B: depthwise conv 3x3 (from NHWC) + LN + GELU -> x1
__global__ __launch_bounds__(128) void k_dwln2(const float* __restrict__ xT,
    const float* __restrict__ dw_w, const float* __restrict__ dw_b,
    const float* __restrict__ ln_g, const float* __restrict__ ln_b,
    float* __restrict__ x1) {
  int pix = blockIdx.x;
  int w = pix % WW; int h = (pix / WW) % HH; int n = pix / SS;
  int c = threadIdx.x;
  const float* src = xT + (size_t)n*SS*CCH + c;
  float s = 0.f;
  #pragma unroll
  for (int kh = 0; kh < 3; ++kh) {
    int yy = h - 1 + kh;
    if (yy < 0 || yy >= HH) continue;
    #pragma unroll
    for (int kw = 0; kw < 3; ++kw) {
      int xx = w - 1 + kw;
      if (xx < 0 || xx >= WW) continue;
      s = fmaf(src[(size_t)(yy*WW + xx)*CCH], dw_w[c*9 + kh*3 + kw], s);
    }
  }
  s += dw_b[c];
  // LayerNorm over 128 channels: wave shuffle reduce (sum, sumsq), 1 barrier
  float s1 = s, s2 = s*s;
  #pragma unroll
  for (int m = 32; m >= 1; m >>= 1) {
    s1 += __shfl_xor(s1, m);
    s2 += __shfl_xor(s2, m);
  }
  __shared__ float rs[2][2];
  int wv = c >> 6;
  if ((c & 63) == 0) { rs[wv][0] = s1; rs[wv][1] = s2; }
  __syncthreads();
  float sum = rs[0][0] + rs[1][0];
  float sq  = rs[0][1] + rs[1][1];
  float mean = sum * (1.f/128.f);
  float var  = sq * (1.f/128.f) - mean*mean;
  float v = (s - mean) * rsqrtf(var + 1e-5f) * ln_g[c] + ln_b[c];
  float g = 0.5f * v * (1.f + erff(v * 0.70710678f));
  x1[(size_t)pix*CCH + c] = g;
}

// ---------------- Kernel C: offset & mask heads + softmax (4 px/block)
__global__ __launch_bounds__(128) void k_offmask4(const float* __restrict__ x1,
    const float* __restrict__ w_off, const float* __restrict__ b_off,
    const float* __restrict__ w_mask, const float* __restrict__ b_mask,
    float* __restrict__ off, float* __restrict__ mask) {
  __shared__ float xs[4][CCH];
  __shared__ float ml[4][GG*PP];
  int p0 = blockIdx.x * 4;
  int t = threadIdx.x;
  ((float4*)xs)[t] = ((const float4*)(x1 + (size_t)p0*CCH))[t];
  __syncthreads();
  if (t < GG*PP*2) {            // 72 offset outputs
    float a0 = b_off[t], a1 = a0, a2 = a0, a3 = a0;
    #pragma unroll 4
    for (int k = 0; k < CCH; ++k) {
      float wv = w_off[k*(GG*PP*2) + t];
      a0 = fmaf(xs[0][k], wv, a0);
      a1 = fmaf(xs[1][k], wv, a1);
      a2 = fmaf(xs[2][k], wv, a2);
      a3 = fmaf(xs[3][k], wv, a3);
    }
    off[(size_t)(p0+0)*(GG*PP*2) + t] = a0;
    off[(size_t)(p0+1)*(GG*PP*2) + t] = a1;
    off[(size_t)(p0+2)*(GG*PP*2) + t] = a2;
    off[(size_t)(p0+3)*(GG*PP*2) + t] = a3;
  } else if (t < GG*PP*3) {     // 36 mask logits
    int j = t - GG*PP*2;
    float a0 = b_mask[j], a1 = a0, a2 = a0, a3 = a0;
    #pragma unroll 4
    for (int k = 0; k < CCH; ++k) {
      float wv = w_mask[k*(GG*PP) + j];
      a0 = fmaf(xs[0][k], wv, a0);
      a1 = fmaf(xs[1][k], wv, a1);
      a2 = fmaf(xs[2][k], wv, a2);
      a3 = fmaf(xs[3][k], wv, a3);
    }
    ml[0][j] = a0; ml[1][j] = a1; ml[2][j] = a2; ml[3][j] = a3;
  }
  __syncthreads();
  if (t >= GG*PP*2 && t < GG*PP*3) {
    int j = t - GG*PP*2;
    int g = j / PP;
    #pragma unroll
    for (int i = 0; i < 4; ++i) {
      float mx = -1e30f;
      #pragma unroll
      for (int q = 0; q < PP; ++q) mx = fmaxf(mx, ml[i][g*PP + q]);
      float sum = 0.f;
      #pragma unroll
      for (int q = 0; q < PP; ++q) sum += __expf(ml[i][g*PP + q] - mx);
      mask[(size_t)(p0+i)*(GG*PP) + j] = __expf(ml[i][j] - mx) / sum;
    }
  }
}

// ---------------- Kernel D: DCNv3 bilinear sampling (2 px/block)
__global__ __launch_bounds__(256) void k_dcn2(const float* __restrict__ xp,
    const float* __restrict__ off, const float* __restrict__ mask,
    float* __restrict__ dcn) {
  __shared__ float offs[2][GG*PP*2];
  __shared__ float ms[2][GG*PP];
  int pb = blockIdx.x * 2;
  int t = threadIdx.x;
  int sub = t >> 7, tl = t & 127;
  int pix = pb + sub;
  if (tl < GG*PP*2) offs[sub][tl] = off[(size_t)pix*(GG*PP*2) + tl];
  else if (tl < GG*PP*3) ms[sub][tl - GG*PP*2] = mask[(size_t)pix*(GG*PP) + (tl - GG*PP*2)];
  __syncthreads();
  int w = pix % WW; int h = (pix / WW) % HH; int n = pix / SS;
  int g = tl >> 5, cc = tl & 31;
  const float* base = xp + (size_t)n*SS*CCH + g*GC + cc;
  float acc = 0.f;
  #pragma unroll
  for (int p = 0; p < PP; ++p) {
    float offx = offs[sub][(g*PP + p)*2 + 0];
    float offy = offs[sub][(g*PP + p)*2 + 1];
    float ix = (float)w + 1.0f + (float)(p / 3 - 1) + offx;
    float iy = (float)h + 1.0f + (float)(p % 3 - 1) + offy;
    float x0f = floorf(ix), y0f = floorf(iy);
    float wx1 = ix - x0f, wx0 = 1.f - wx1;
    float wy1 = iy - y0f, wy0 = 1.f - wy1;
    int x0i = (int)x0f, y0i = (int)y0f;
    int ox0 = x0i - 1, oy0 = y0i - 1;   // padded -> original coords
    int ox1 = x0i,     oy1 = y0i;
    float v = 0.f;
    if (oy0 >= 0 && oy0 < HH) {
      if (ox0 >= 0 && ox0 < WW) v = fmaf(wy0*wx0, base[(size_t)(oy0*WW + ox0)*CCH], v);
      if (ox1 >= 0 && ox1 < WW) v = fmaf(wy0*wx1, base[(size_t)(oy0*WW + ox1)*CCH], v);
    }
    if (oy1 >= 0 && oy1 < HH) {
      if (ox0 >= 0 && ox0 < WW) v = fmaf(wy1*wx0, base[(size_t)(oy1*WW + ox0)*CCH], v);
      if (ox1 >= 0 && ox1 < WW) v = fmaf(wy1*wx1, base[(size_t)(oy1*WW + ox1)*CCH], v);
    }
    acc = fmaf(ms[sub][g*PP + p], v, acc);
  }
  dcn[(size_t)pix*CCH + tl] = acc;
}

// ---------------- Kernel E: output projection -> o NHWC (4 px/block)
__global__ __launch_bounds__(128) void k_outproj4(const float* __restrict__ dcn,
    const float* __restrict__ w_out, const float* __restrict__ b_out,
    float* __restrict__ o) {
  __shared__ float xs[4][CCH];
  int p0 = blockIdx.x * 4;
  int t = threadIdx.x;
  ((float4*)xs)[t] = ((const float4*)(dcn + (size_t)p0*CCH))[t];
  __syncthreads();
  int c = t;
  float a0 = b_out[c], a1 = a0, a2 = a0, a3 = a0;
  #pragma unroll 4
  for (int k = 0; k < CCH; ++k) {
    float wv = w_out[k*CCH + c];
    a0 = fmaf(xs[0][k], wv, a0);
    a1 = fmaf(xs[1][k], wv, a1);
    a2 = fmaf(xs[2][k], wv, a2);
    a3 = fmaf(xs[3][k], wv, a3);
  }
  o[(size_t)(p0+0)*CCH + c] = a0;
  o[(size_t)(p0+1)*CCH + c] = a1;
  o[(size_t)(p0+2)*CCH + c] = a2;
  o[(size_t)(p0+3)*CCH + c] = a3;
}

extern "C" void kernel_launch(void* const* d_in, const int* in_sizes, int n_in,
                              void* d_out, int out_size, void* d_ws, size_t ws_size,
                              hipStream_t stream) {
  const float* x       = (const float*)d_in[0];
  const float* dw_w    = (const float*)d_in[1];
  const float* dw_b    = (const float*)d_in[2];
  const float* ln_g    = (const float*)d_in[3];
  const float* ln_b    = (const float*)d_in[4];
  const float* w_off   = (const float*)d_in[5];
  const float* b_off   = (const float*)d_in[6];
  const float* w_mask  = (const float*)d_in[7];
  const float* b_mask  = (const float*)d_in[8];
  const float* w_in    = (const float*)d_in[9];
  const float* b_in    = (const float*)d_in[10];
  const float* w_out   = (const float*)d_in[11];
  const float* b_out   = (const float*)d_in[12];
  const float* bn_g    = (const float*)d_in[13];
  const float* bn_b    = (const float*)d_in[14];
  const float* bn_mean = (const float*)d_in[15];
  const float* bn_var  = (const float*)d_in[16];
  float* y = (float*)d_out;

  // buffer plan (aliased): buf0 = xT then o; buf1 = xp; buf2 = x1 then dcn
  float* buf0 = (float*)d_ws;                    // NPIX*128
  float* buf1 = buf0 + (size_t)NPIX*CCH;         // NPIX*128
  float* buf2 = buf1 + (size_t)NPIX*CCH;         // NPIX*128
  float* offb = buf2 + (size_t)NPIX*CCH;         // NPIX*72
  float* mb   = offb + (size_t)NPIX*(GG*PP*2);   // NPIX*36
  float* xT  = buf0;
  float* xp  = buf1;
  float* x1  = buf2;
  float* dcn = buf2;   // alias: x1 dead after k_offmask4
  float* o   = buf0;   // alias: xT dead after k_dwln2

  dim3 trg(SS/32, CCH/32, NN), trb(32, 8);
  k_tr_in<<<trg, trb, 0, stream>>>(x, xT);
  k_proj4<<<NPIX/4, 128, 0, stream>>>(xT, w_in, b_in, xp);
  k_dwln2<<<NPIX, 128, 0, stream>>>(xT, dw_w, dw_b, ln_g, ln_b, x1);
  k_offmask4<<<NPIX/4, 128, 0, stream>>>(x1, w_off, b_off, w_mask, b_mask, offb, mb);
  k_dcn2<<<NPIX/2, 256, 0, stream>>>(xp, offb, mb, dcn);
  k_outproj4<<<NPIX/4, 128, 0, stream>>>(dcn, w_out, b_out, o);
  k_tr_out<<<trg, trb, 0, stream>>>(o, bn_g, bn_b, bn_mean, bn_var, y);
}

// Round 3
// 264.941 us; speedup vs baseline: 2.5016x; 1.4041x over previous
//
#include <hip/hip_runtime.h>
#include <math.h>

#define NN 4
#define CCH 128
#define HH 96
#define WW 96
#define SS (HH*WW)          // 9216 pixels per image
#define GG 4
#define GC 32
#define PP 9
#define NPIX (NN*HH*WW)     // 36864

// ---------------- Transpose in: x NCHW -> xT NHWC
__global__ __launch_bounds__(256) void k_tr_in(const float* __restrict__ x,
                                               float* __restrict__ xT) {
  __shared__ float tile[32][33];
  int n = blockIdx.z;
  int cs = blockIdx.y * 32;
  int ps = blockIdx.x * 32;
  int tx = threadIdx.x;
  int ty = threadIdx.y;
  const float* src = x + ((size_t)n*CCH)*SS;
  #pragma unroll
  for (int i = 0; i < 4; ++i) {
    int r = ty + i*8;
    tile[r][tx] = src[(size_t)(cs + r)*SS + ps + tx];
  }
  __syncthreads();
  float* dst = xT + (size_t)n*SS*CCH;
  #pragma unroll
  for (int i = 0; i < 4; ++i) {
    int r = ty + i*8;
    dst[(size_t)(ps + r)*CCH + cs + tx] = tile[tx][r];
  }
}

// ---------------- input projection xp = xT @ w_in + b_in (8 px/block)
__global__ __launch_bounds__(128) void k_proj8(const float* __restrict__ xT,
    const float* __restrict__ w_in, const float* __restrict__ b_in,
    float* __restrict__ xp) {
  __shared__ float xs[8][CCH];
  int p0 = blockIdx.x * 8;
  int t = threadIdx.x;
  const float4* srcv = (const float4*)(xT + (size_t)p0*CCH);
  ((float4*)xs)[t] = srcv[t];
  ((float4*)xs)[t + 128] = srcv[t + 128];
  __syncthreads();
  int c = t;
  float a[8];
  float b0 = b_in[c];
  #pragma unroll
  for (int j = 0; j < 8; ++j) a[j] = b0;
  #pragma unroll 4
  for (int k = 0; k < CCH; ++k) {
    float wv = w_in[k*CCH + c];
    #pragma unroll
    for (int j = 0; j < 8; ++j) a[j] = fmaf(xs[j][k], wv, a[j]);
  }
  #pragma unroll
  for (int j = 0; j < 8; ++j) xp[(size_t)(p0+j)*CCH + c] = a[j];
}

// ---------------- fused: dwconv3x3 + LN + GELU + offset/mask heads + softmax (4 px/block)
__global__ __launch_bounds__(128) void k_dwom4(const float* __restrict__ xT,
    const float* __restrict__ dw_w, const float* __restrict__ dw_b,
    const float* __restrict__ ln_g, const float* __restrict__ ln_b,
    const float* __restrict__ w_off, const float* __restrict__ b_off,
    const float* __restrict__ w_mask, const float* __restrict__ b_mask,
    float* __restrict__ off, float* __restrict__ mask) {
  __shared__ float xs[4][CCH];
  __shared__ float ml[4][GG*PP];
  __shared__ float rs[4][2][2];
  int blk = blockIdx.x;
  const int W4 = WW/4;
  int w0 = (blk % W4) * 4;
  int h  = (blk / W4) % HH;
  int n  = blk / (W4*HH);
  int c  = threadIdx.x;
  const float* src = xT + (size_t)n*SS*CCH + c;
  // sliding 3x6 window of this channel
  float r[3][6];
  #pragma unroll
  for (int kh = 0; kh < 3; ++kh) {
    int yy = h - 1 + kh;
    bool yok = (yy >= 0 && yy < HH);
    #pragma unroll
    for (int i = 0; i < 6; ++i) {
      int xx = w0 - 1 + i;
      r[kh][i] = (yok && xx >= 0 && xx < WW) ? src[(size_t)(yy*WW + xx)*CCH] : 0.f;
    }
  }
  float wt[9];
  #pragma unroll
  for (int j = 0; j < 9; ++j) wt[j] = dw_w[c*9 + j];
  float bias = dw_b[c], lg = ln_g[c], lb = ln_b[c];
  float sv[4];
  #pragma unroll
  for (int j = 0; j < 4; ++j) {
    float s = bias;
    #pragma unroll
    for (int kh = 0; kh < 3; ++kh)
      #pragma unroll
      for (int kw = 0; kw < 3; ++kw)
        s = fmaf(r[kh][j + kw], wt[kh*3 + kw], s);
    sv[j] = s;
    float s1 = s, s2 = s*s;
    #pragma unroll
    for (int m = 32; m >= 1; m >>= 1) {
      s1 += __shfl_xor(s1, m);
      s2 += __shfl_xor(s2, m);
    }
    if ((c & 63) == 0) { rs[j][c>>6][0] = s1; rs[j][c>>6][1] = s2; }
  }
  __syncthreads();
  #pragma unroll
  for (int j = 0; j < 4; ++j) {
    float sum = rs[j][0][0] + rs[j][1][0];
    float sq  = rs[j][0][1] + rs[j][1][1];
    float mean = sum * (1.f/128.f);
    float var  = sq * (1.f/128.f) - mean*mean;
    float v = (sv[j] - mean) * rsqrtf(var + 1e-5f) * lg + lb;
    xs[j][c] = 0.5f * v * (1.f + erff(v * 0.70710678f));
  }
  __syncthreads();
  size_t pix0 = (size_t)(n*HH + h)*WW + w0;
  if (c < GG*PP*2) {                 // 72 offset outputs
    float a0 = b_off[c], a1 = a0, a2 = a0, a3 = a0;
    #pragma unroll 4
    for (int k = 0; k < CCH; ++k) {
      float wv = w_off[k*(GG*PP*2) + c];
      a0 = fmaf(xs[0][k], wv, a0);
      a1 = fmaf(xs[1][k], wv, a1);
      a2 = fmaf(xs[2][k], wv, a2);
      a3 = fmaf(xs[3][k], wv, a3);
    }
    off[(pix0+0)*(GG*PP*2) + c] = a0;
    off[(pix0+1)*(GG*PP*2) + c] = a1;
    off[(pix0+2)*(GG*PP*2) + c] = a2;
    off[(pix0+3)*(GG*PP*2) + c] = a3;
  } else if (c < GG*PP*3) {          // 36 mask logits
    int j2 = c - GG*PP*2;
    float a0 = b_mask[j2], a1 = a0, a2 = a0, a3 = a0;
    #pragma unroll 4
    for (int k = 0; k < CCH; ++k) {
      float wv = w_mask[k*(GG*PP) + j2];
      a0 = fmaf(xs[0][k], wv, a0);
      a1 = fmaf(xs[1][k], wv, a1);
      a2 = fmaf(xs[2][k], wv, a2);
      a3 = fmaf(xs[3][k], wv, a3);
    }
    ml[0][j2] = a0; ml[1][j2] = a1; ml[2][j2] = a2; ml[3][j2] = a3;
  }
  __syncthreads();
  if (c >= GG*PP*2 && c < GG*PP*3) {
    int j2 = c - GG*PP*2;
    int g = j2 / PP;
    #pragma unroll
    for (int i = 0; i < 4; ++i) {
      float mx = -1e30f;
      #pragma unroll
      for (int q = 0; q < PP; ++q) mx = fmaxf(mx, ml[i][g*PP + q]);
      float sum = 0.f;
      #pragma unroll
      for (int q = 0; q < PP; ++q) sum += __expf(ml[i][g*PP + q] - mx);
      mask[(pix0+i)*(GG*PP) + j2] = __expf(ml[i][j2] - mx) / sum;
    }
  }
}

// ---------------- DCNv3 bilinear sampling, float4 channels (8 px/block)
__global__ __launch_bounds__(256) void k_dcn8(const float* __restrict__ xp,
    const float* __restrict__ off, const float* __restrict__ mask,
    float* __restrict__ dcn) {
  __shared__ float offs[8][GG*PP*2];
  __shared__ float ms[8][GG*PP];
  int pb = blockIdx.x * 8;
  int t = threadIdx.x;
  {
    const float* po = off + (size_t)pb*(GG*PP*2);
    for (int i = t; i < 8*GG*PP*2; i += 256) ((float*)offs)[i] = po[i];
    const float* pm = mask + (size_t)pb*(GG*PP);
    for (int i = t; i < 8*GG*PP; i += 256) ((float*)ms)[i] = pm[i];
  }
  __syncthreads();
  int sub = t >> 5, tl = t & 31;
  int pix = pb + sub;
  int g = tl >> 3, q = tl & 7;
  int w = pix % WW; int h = (pix / WW) % HH; int n = pix / SS;
  const float4* base = (const float4*)(xp + (size_t)n*SS*CCH + g*GC) + q;
  float4 acc = {0.f, 0.f, 0.f, 0.f};
  #pragma unroll
  for (int p = 0; p < PP; ++p) {
    float offx = offs[sub][(g*PP + p)*2 + 0];
    float offy = offs[sub][(g*PP + p)*2 + 1];
    float ix = (float)w + 1.0f + (float)(p / 3 - 1) + offx;
    float iy = (float)h + 1.0f + (float)(p % 3 - 1) + offy;
    float x0f = floorf(ix), y0f = floorf(iy);
    float wx1 = ix - x0f, wx0 = 1.f - wx1;
    float wy1 = iy - y0f, wy0 = 1.f - wy1;
    int x0i = (int)x0f, y0i = (int)y0f;
    int ox0 = x0i - 1, oy0 = y0i - 1;   // padded -> original
    int ox1 = x0i,     oy1 = y0i;
    float4 v = {0.f, 0.f, 0.f, 0.f};
    if (oy0 >= 0 && oy0 < HH) {
      if (ox0 >= 0 && ox0 < WW) {
        float4 u = base[(size_t)(oy0*WW + ox0)*32];
        float wgt = wy0*wx0;
        v.x = fmaf(wgt, u.x, v.x); v.y = fmaf(wgt, u.y, v.y);
        v.z = fmaf(wgt, u.z, v.z); v.w = fmaf(wgt, u.w, v.w);
      }
      if (ox1 >= 0 && ox1 < WW) {
        float4 u = base[(size_t)(oy0*WW + ox1)*32];
        float wgt = wy0*wx1;
        v.x = fmaf(wgt, u.x, v.x); v.y = fmaf(wgt, u.y, v.y);
        v.z = fmaf(wgt, u.z, v.z); v.w = fmaf(wgt, u.w, v.w);
      }
    }
    if (oy1 >= 0 && oy1 < HH) {
      if (ox0 >= 0 && ox0 < WW) {
        float4 u = base[(size_t)(oy1*WW + ox0)*32];
        float wgt = wy1*wx0;
        v.x = fmaf(wgt, u.x, v.x); v.y = fmaf(wgt, u.y, v.y);
        v.z = fmaf(wgt, u.z, v.z); v.w = fmaf(wgt, u.w, v.w);
      }
      if (ox1 >= 0 && ox1 < WW) {
        float4 u = base[(size_t)(oy1*WW + ox1)*32];
        float wgt = wy1*wx1;
        v.x = fmaf(wgt, u.x, v.x); v.y = fmaf(wgt, u.y, v.y);
        v.z = fmaf(wgt, u.z, v.z); v.w = fmaf(wgt, u.w, v.w);
      }
    }
    float mval = ms[sub][g*PP + p];
    acc.x = fmaf(mval, v.x, acc.x); acc.y = fmaf(mval, v.y, acc.y);
    acc.z = fmaf(mval, v.z, acc.z); acc.w = fmaf(mval, v.w, acc.w);
  }
  ((float4*)(dcn + (size_t)pix*CCH + g*GC))[q] = acc;
}

// ---------------- output projection + BN + SiLU + NCHW write (32 px/block)
__global__ __launch_bounds__(256) void k_outbn32(const float* __restrict__ dcn,
    const float* __restrict__ w_out, const float* __restrict__ b_out,
    const float* __restrict__ bn_g, const float* __restrict__ bn_b,
    const float* __restrict__ bn_mean, const float* __restrict__ bn_var,
    float* __restrict__ y) {
  __shared__ float xs[32][132];   // padded rows: float4-aligned, 4-way bank spread
  int blk = blockIdx.x;
  int s0 = blk * 32;              // 32 consecutive pixels, same n and h (96%32==0)
  int t = threadIdx.x;
  const float4* srcv = (const float4*)(dcn + (size_t)s0*CCH);
  #pragma unroll
  for (int i = 0; i < 4; ++i) {
    int f = t + i*256;            // float4 index: px = f>>5, c4 = f&31
    float4 u = srcv[f];
    ((float4*)(&xs[f >> 5][0]))[f & 31] = u;
  }
  __syncthreads();
  int c = t & 127, half = t >> 7;
  float acc[16];
  float b0 = b_out[c];
  #pragma unroll
  for (int i = 0; i < 16; ++i) acc[i] = b0;
  #pragma unroll 4
  for (int k = 0; k < CCH; ++k) {
    float wv = w_out[k*CCH + c];
    #pragma unroll
    for (int i = 0; i < 16; ++i) acc[i] = fmaf(xs[half*16 + i][k], wv, acc[i]);
  }
  __syncthreads();
  float inv_ = rsqrtf(bn_var[c] + 1e-5f);
  float sc = inv_ * bn_g[c];
  float sh = bn_b[c] - bn_mean[c] * sc;
  #pragma unroll
  for (int i = 0; i < 16; ++i) {
    float v = acc[i] * sc + sh;
    float sig = 1.f / (1.f + __expf(-v));
    xs[half*16 + i][c] = v * sig;
  }
  __syncthreads();
  int w0 = s0 % WW;
  int h  = (s0 / WW) % HH;
  int n  = s0 / SS;
  int px = t & 31, cb = t >> 5;   // 8 channel groups
  float* dst = y + ((size_t)n*CCH)*SS + (size_t)h*WW + w0 + px;
  #pragma unroll
  for (int i = 0; i < 16; ++i) {
    int cc = cb + i*8;
    dst[(size_t)cc*SS] = xs[px][cc];
  }
}

extern "C" void kernel_launch(void* const* d_in, const int* in_sizes, int n_in,
                              void* d_out, int out_size, void* d_ws, size_t ws_size,
                              hipStream_t stream) {
  const float* x       = (const float*)d_in[0];
  const float* dw_w    = (const float*)d_in[1];
  const float* dw_b    = (const float*)d_in[2];
  const float* ln_g    = (const float*)d_in[3];
  const float* ln_b    = (const float*)d_in[4];
  const float* w_off   = (const float*)d_in[5];
  const float* b_off   = (const float*)d_in[6];
  const float* w_mask  = (const float*)d_in[7];
  const float* b_mask  = (const float*)d_in[8];
  const float* w_in    = (const float*)d_in[9];
  const float* b_in    = (const float*)d_in[10];
  const float* w_out   = (const float*)d_in[11];
  const float* b_out   = (const float*)d_in[12];
  const float* bn_g    = (const float*)d_in[13];
  const float* bn_b    = (const float*)d_in[14];
  const float* bn_mean = (const float*)d_in[15];
  const float* bn_var  = (const float*)d_in[16];
  float* y = (float*)d_out;

  float* xT   = (float*)d_ws;                    // NPIX*128
  float* xp   = xT   + (size_t)NPIX*CCH;         // NPIX*128
  float* dcn  = xp   + (size_t)NPIX*CCH;         // NPIX*128
  float* offb = dcn  + (size_t)NPIX*CCH;         // NPIX*72
  float* mb   = offb + (size_t)NPIX*(GG*PP*2);   // NPIX*36

  dim3 trg(SS/32, CCH/32, NN), trb(32, 8);
  k_tr_in<<<trg, trb, 0, stream>>>(x, xT);
  k_proj8<<<NPIX/8, 128, 0, stream>>>(xT, w_in, b_in, xp);
  k_dwom4<<<NPIX/4, 128, 0, stream>>>(xT, dw_w, dw_b, ln_g, ln_b,
                                      w_off, b_off, w_mask, b_mask, offb, mb);
  k_dcn8<<<NPIX/8, 256, 0, stream>>>(xp, offb, mb, dcn);
  k_outbn32<<<NPIX/32, 256, 0, stream>>>(dcn, w_out, b_out,
                                         bn_g, bn_b, bn_mean, bn_var, y);
}

// Round 4
// 217.397 us; speedup vs baseline: 3.0487x; 1.2187x over previous
//
#include <hip/hip_runtime.h>
#include <math.h>

#define NN 4
#define CCH 128
#define HH 96
#define WW 96
#define SS (HH*WW)          // 9216
#define GG 4
#define GC 32
#define PP 9
#define NPIX (NN*HH*WW)     // 36864

typedef short bf16x8 __attribute__((ext_vector_type(8)));
typedef float f32x4 __attribute__((ext_vector_type(4)));
typedef unsigned short u16;

static __device__ __forceinline__ u16 f2bf(float f) {
  unsigned u = __builtin_bit_cast(unsigned, f);
  unsigned r = (u + 0x7fffu + ((u >> 16) & 1u)) >> 16;  // RNE
  return (u16)r;
}

// ---------------- prep: transpose + bf16-convert weights (runs every call, ~2us)
// rows 0..127: w_inT[c][k]; 128..239: w_omT[c][k] (c<72 off, 72..107 mask, pad 0); 240..367: w_outT
__global__ __launch_bounds__(128) void k_prep(const float* __restrict__ w_in,
    const float* __restrict__ w_off, const float* __restrict__ w_mask,
    const float* __restrict__ w_out,
    u16* __restrict__ w_inT, u16* __restrict__ w_omT, u16* __restrict__ w_outT) {
  int r = blockIdx.x, k = threadIdx.x;
  if (r < 128) {
    w_inT[r*128 + k] = f2bf(w_in[k*128 + r]);
  } else if (r < 240) {
    int c = r - 128;
    float v = 0.f;
    if (c < 72) v = w_off[k*72 + c];
    else if (c < 108) v = w_mask[k*36 + (c - 72)];
    w_omT[c*128 + k] = f2bf(v);
  } else {
    int c = r - 240;
    w_outT[c*128 + k] = f2bf(w_out[k*128 + c]);
  }
}

// ---------------- Transpose in: x NCHW -> xT (fp32 NHWC) + xTb (bf16 NHWC)
__global__ __launch_bounds__(256) void k_tr_in(const float* __restrict__ x,
    float* __restrict__ xT, u16* __restrict__ xTb) {
  __shared__ float tile[32][33];
  int n = blockIdx.z;
  int cs = blockIdx.y * 32;
  int ps = blockIdx.x * 32;
  int tx = threadIdx.x;
  int ty = threadIdx.y;
  const float* src = x + ((size_t)n*CCH)*SS;
  #pragma unroll
  for (int i = 0; i < 4; ++i) {
    int r = ty + i*8;
    tile[r][tx] = src[(size_t)(cs + r)*SS + ps + tx];
  }
  __syncthreads();
  float* dst = xT + (size_t)n*SS*CCH;
  u16* dstb = xTb + (size_t)n*SS*CCH;
  #pragma unroll
  for (int i = 0; i < 4; ++i) {
    int r = ty + i*8;
    float v = tile[tx][r];
    dst[(size_t)(ps + r)*CCH + cs + tx] = v;
    dstb[(size_t)(ps + r)*CCH + cs + tx] = f2bf(v);
  }
}

// ---------------- input projection: xp = xTb @ w_inT^T + b_in  (MFMA, 64px/block)
__global__ __launch_bounds__(256) void k_proj_mfma(const u16* __restrict__ xTb,
    const u16* __restrict__ wT, const float* __restrict__ bias,
    float* __restrict__ xp) {
  int t = threadIdx.x;
  int wv = t >> 6, l = t & 63;
  int c16 = l & 15, kq = l >> 4;        // A-row / B-col = c16 ; k-quarter = kq
  int px0 = blockIdx.x*64 + wv*16;
  const u16* arow = xTb + (size_t)(px0 + c16)*CCH + kq*8;
  f32x4 acc[8] = {};
  #pragma unroll
  for (int ks = 0; ks < 4; ++ks) {
    bf16x8 a = *(const bf16x8*)(arow + ks*32);
    #pragma unroll
    for (int nt = 0; nt < 8; ++nt) {
      bf16x8 b = *(const bf16x8*)(wT + (size_t)(nt*16 + c16)*CCH + ks*32 + kq*8);
      acc[nt] = __builtin_amdgcn_mfma_f32_16x16x32_bf16(a, b, acc[nt], 0, 0, 0);
    }
  }
  #pragma unroll
  for (int nt = 0; nt < 8; ++nt) {
    int c = nt*16 + c16;
    float bs = bias[c];
    #pragma unroll
    for (int r = 0; r < 4; ++r) {
      int px = px0 + kq*4 + r;
      xp[(size_t)px*CCH + c] = acc[nt][r] + bs;
    }
  }
}

// ---------------- dwconv3x3 + LN + GELU -> x1b bf16 (8 px/block)
__global__ __launch_bounds__(128) void k_dwln8(const float* __restrict__ xT,
    const float* __restrict__ dw_w, const float* __restrict__ dw_b,
    const float* __restrict__ ln_g, const float* __restrict__ ln_b,
    u16* __restrict__ x1b) {
  __shared__ float rs[8][2][2];
  int blk = blockIdx.x;
  const int W8 = WW/8;
  int w0 = (blk % W8) * 8;
  int h  = (blk / W8) % HH;
  int n  = blk / (W8*HH);
  int c  = threadIdx.x;
  const float* src = xT + (size_t)n*SS*CCH + c;
  float r[3][10];
  #pragma unroll
  for (int kh = 0; kh < 3; ++kh) {
    int yy = h - 1 + kh;
    bool yok = (yy >= 0 && yy < HH);
    #pragma unroll
    for (int i = 0; i < 10; ++i) {
      int xx = w0 - 1 + i;
      r[kh][i] = (yok && xx >= 0 && xx < WW) ? src[(size_t)(yy*WW + xx)*CCH] : 0.f;
    }
  }
  float wt[9];
  #pragma unroll
  for (int j = 0; j < 9; ++j) wt[j] = dw_w[c*9 + j];
  float bias = dw_b[c], lg = ln_g[c], lb = ln_b[c];
  float sv[8];
  #pragma unroll
  for (int j = 0; j < 8; ++j) {
    float s = bias;
    #pragma unroll
    for (int kh = 0; kh < 3; ++kh)
      #pragma unroll
      for (int kw = 0; kw < 3; ++kw)
        s = fmaf(r[kh][j + kw], wt[kh*3 + kw], s);
    sv[j] = s;
    float s1 = s, s2 = s*s;
    #pragma unroll
    for (int m = 32; m >= 1; m >>= 1) {
      s1 += __shfl_xor(s1, m);
      s2 += __shfl_xor(s2, m);
    }
    if ((c & 63) == 0) { rs[j][c>>6][0] = s1; rs[j][c>>6][1] = s2; }
  }
  __syncthreads();
  size_t pix0 = (size_t)(n*HH + h)*WW + w0;
  #pragma unroll
  for (int j = 0; j < 8; ++j) {
    float sum = rs[j][0][0] + rs[j][1][0];
    float sq  = rs[j][0][1] + rs[j][1][1];
    float mean = sum * (1.f/128.f);
    float var  = sq * (1.f/128.f) - mean*mean;
    float v = (sv[j] - mean) * rsqrtf(var + 1e-5f) * lg + lb;
    float g = 0.5f * v * (1.f + erff(v * 0.70710678f));
    x1b[(pix0 + j)*CCH + c] = f2bf(g);
  }
}

// ---------------- offset/mask heads (MFMA, 64px/block) + fused softmax
__global__ __launch_bounds__(256) void k_om_mfma(const u16* __restrict__ x1b,
    const u16* __restrict__ wT, const float* __restrict__ b_off,
    const float* __restrict__ b_mask,
    float* __restrict__ off, float* __restrict__ mask) {
  __shared__ float xs[64][116];
  int t = threadIdx.x;
  int wv = t >> 6, l = t & 63;
  int c16 = l & 15, kq = l >> 4;
  int px0b = blockIdx.x*64;
  int px0 = px0b + wv*16;
  const u16* arow = x1b + (size_t)(px0 + c16)*CCH + kq*8;
  f32x4 acc[7] = {};
  #pragma unroll
  for (int ks = 0; ks < 4; ++ks) {
    bf16x8 a = *(const bf16x8*)(arow + ks*32);
    #pragma unroll
    for (int nt = 0; nt < 7; ++nt) {
      bf16x8 b = *(const bf16x8*)(wT + (size_t)(nt*16 + c16)*CCH + ks*32 + kq*8);
      acc[nt] = __builtin_amdgcn_mfma_f32_16x16x32_bf16(a, b, acc[nt], 0, 0, 0);
    }
  }
  #pragma unroll
  for (int nt = 0; nt < 7; ++nt) {
    int c = nt*16 + c16;
    float bs = (c < 72) ? b_off[c] : ((c < 108) ? b_mask[c - 72] : 0.f);
    #pragma unroll
    for (int r = 0; r < 4; ++r)
      xs[wv*16 + kq*4 + r][c] = acc[nt][r] + bs;
  }
  __syncthreads();
  // offsets: 64px x 72 cols
  for (int i = t; i < 64*72; i += 256) {
    int px = i / 72, j = i - px*72;
    off[(size_t)(px0b + px)*72 + j] = xs[px][j];
  }
  // masks: 64px x 4 groups, softmax over 9
  {
    int px = t >> 2, g = t & 3;
    float mx = -1e30f;
    #pragma unroll
    for (int q = 0; q < PP; ++q) mx = fmaxf(mx, xs[px][72 + g*9 + q]);
    float e[9]; float sum = 0.f;
    #pragma unroll
    for (int q = 0; q < PP; ++q) { e[q] = __expf(xs[px][72 + g*9 + q] - mx); sum += e[q]; }
    float inv = 1.f / sum;
    #pragma unroll
    for (int q = 0; q < PP; ++q)
      mask[(size_t)(px0b + px)*36 + g*9 + q] = e[q] * inv;
  }
}

// ---------------- DCNv3 bilinear sampling (8 px/block), fp32 in, bf16 out
__global__ __launch_bounds__(256) void k_dcn8(const float* __restrict__ xp,
    const float* __restrict__ off, const float* __restrict__ mask,
    u16* __restrict__ dcnb) {
  __shared__ float offs[8][GG*PP*2];
  __shared__ float ms[8][GG*PP];
  int pb = blockIdx.x * 8;
  int t = threadIdx.x;
  {
    const float* po = off + (size_t)pb*(GG*PP*2);
    for (int i = t; i < 8*GG*PP*2; i += 256) ((float*)offs)[i] = po[i];
    const float* pm = mask + (size_t)pb*(GG*PP);
    for (int i = t; i < 8*GG*PP; i += 256) ((float*)ms)[i] = pm[i];
  }
  __syncthreads();
  int sub = t >> 5, tl = t & 31;
  int pix = pb + sub;
  int g = tl >> 3, q = tl & 7;
  int w = pix % WW; int h = (pix / WW) % HH; int n = pix / SS;
  const float4* base = (const float4*)(xp + (size_t)n*SS*CCH + g*GC) + q;
  float4 acc = {0.f, 0.f, 0.f, 0.f};
  #pragma unroll
  for (int p = 0; p < PP; ++p) {
    float offx = offs[sub][(g*PP + p)*2 + 0];
    float offy = offs[sub][(g*PP + p)*2 + 1];
    float ix = (float)w + 1.0f + (float)(p / 3 - 1) + offx;
    float iy = (float)h + 1.0f + (float)(p % 3 - 1) + offy;
    float x0f = floorf(ix), y0f = floorf(iy);
    float wx1 = ix - x0f, wx0 = 1.f - wx1;
    float wy1 = iy - y0f, wy0 = 1.f - wy1;
    int x0i = (int)x0f, y0i = (int)y0f;
    int ox0 = x0i - 1, oy0 = y0i - 1;   // padded -> original
    int ox1 = x0i,     oy1 = y0i;
    float4 v = {0.f, 0.f, 0.f, 0.f};
    if (oy0 >= 0 && oy0 < HH) {
      if (ox0 >= 0 && ox0 < WW) {
        float4 u = base[(size_t)(oy0*WW + ox0)*32];
        float wgt = wy0*wx0;
        v.x = fmaf(wgt, u.x, v.x); v.y = fmaf(wgt, u.y, v.y);
        v.z = fmaf(wgt, u.z, v.z); v.w = fmaf(wgt, u.w, v.w);
      }
      if (ox1 >= 0 && ox1 < WW) {
        float4 u = base[(size_t)(oy0*WW + ox1)*32];
        float wgt = wy0*wx1;
        v.x = fmaf(wgt, u.x, v.x); v.y = fmaf(wgt, u.y, v.y);
        v.z = fmaf(wgt, u.z, v.z); v.w = fmaf(wgt, u.w, v.w);
      }
    }
    if (oy1 >= 0 && oy1 < HH) {
      if (ox0 >= 0 && ox0 < WW) {
        float4 u = base[(size_t)(oy1*WW + ox0)*32];
        float wgt = wy1*wx0;
        v.x = fmaf(wgt, u.x, v.x); v.y = fmaf(wgt, u.y, v.y);
        v.z = fmaf(wgt, u.z, v.z); v.w = fmaf(wgt, u.w, v.w);
      }
      if (ox1 >= 0 && ox1 < WW) {
        float4 u = base[(size_t)(oy1*WW + ox1)*32];
        float wgt = wy1*wx1;
        v.x = fmaf(wgt, u.x, v.x); v.y = fmaf(wgt, u.y, v.y);
        v.z = fmaf(wgt, u.z, v.z); v.w = fmaf(wgt, u.w, v.w);
      }
    }
    float mval = ms[sub][g*PP + p];
    acc.x = fmaf(mval, v.x, acc.x); acc.y = fmaf(mval, v.y, acc.y);
    acc.z = fmaf(mval, v.z, acc.z); acc.w = fmaf(mval, v.w, acc.w);
  }
  short4 ov;
  ov.x = (short)f2bf(acc.x); ov.y = (short)f2bf(acc.y);
  ov.z = (short)f2bf(acc.z); ov.w = (short)f2bf(acc.w);
  *(short4*)(dcnb + (size_t)pix*CCH + g*GC + q*4) = ov;
}

// ---------------- output projection (MFMA) + BN + SiLU + NCHW write (64px/block)
__global__ __launch_bounds__(256) void k_out_mfma(const u16* __restrict__ dcnb,
    const u16* __restrict__ wT, const float* __restrict__ b_out,
    const float* __restrict__ bn_g, const float* __restrict__ bn_b,
    const float* __restrict__ bn_mean, const float* __restrict__ bn_var,
    float* __restrict__ y) {
  __shared__ float xs[64][133];
  int t = threadIdx.x;
  int wv = t >> 6, l = t & 63;
  int c16 = l & 15, kq = l >> 4;
  int s0 = blockIdx.x*64;
  int px0 = s0 + wv*16;
  const u16* arow = dcnb + (size_t)(px0 + c16)*CCH + kq*8;
  f32x4 acc[8] = {};
  #pragma unroll
  for (int ks = 0; ks < 4; ++ks) {
    bf16x8 a = *(const bf16x8*)(arow + ks*32);
    #pragma unroll
    for (int nt = 0; nt < 8; ++nt) {
      bf16x8 b = *(const bf16x8*)(wT + (size_t)(nt*16 + c16)*CCH + ks*32 + kq*8);
      acc[nt] = __builtin_amdgcn_mfma_f32_16x16x32_bf16(a, b, acc[nt], 0, 0, 0);
    }
  }
  #pragma unroll
  for (int nt = 0; nt < 8; ++nt) {
    int c = nt*16 + c16;
    float bs = b_out[c];
    #pragma unroll
    for (int r = 0; r < 4; ++r)
      xs[wv*16 + kq*4 + r][c] = acc[nt][r] + bs;
  }
  __syncthreads();
  int n = s0 / SS, rem = s0 % SS;
  int pxl = t & 63, cb = t >> 6;
  float* dst = y + ((size_t)n*CCH)*SS + rem + pxl;
  #pragma unroll 4
  for (int i = 0; i < 32; ++i) {
    int c = cb*32 + i;
    float sc = rsqrtf(bn_var[c] + 1e-5f) * bn_g[c];
    float sh = bn_b[c] - bn_mean[c] * sc;
    float v = xs[pxl][c] * sc + sh;
    float sig = 1.f / (1.f + __expf(-v));
    dst[(size_t)c*SS] = v * sig;
  }
}

extern "C" void kernel_launch(void* const* d_in, const int* in_sizes, int n_in,
                              void* d_out, int out_size, void* d_ws, size_t ws_size,
                              hipStream_t stream) {
  const float* x       = (const float*)d_in[0];
  const float* dw_w    = (const float*)d_in[1];
  const float* dw_b    = (const float*)d_in[2];
  const float* ln_g    = (const float*)d_in[3];
  const float* ln_b    = (const float*)d_in[4];
  const float* w_off   = (const float*)d_in[5];
  const float* b_off   = (const float*)d_in[6];
  const float* w_mask  = (const float*)d_in[7];
  const float* b_mask  = (const float*)d_in[8];
  const float* w_in    = (const float*)d_in[9];
  const float* b_in    = (const float*)d_in[10];
  const float* w_out   = (const float*)d_in[11];
  const float* b_out   = (const float*)d_in[12];
  const float* bn_g    = (const float*)d_in[13];
  const float* bn_b    = (const float*)d_in[14];
  const float* bn_mean = (const float*)d_in[15];
  const float* bn_var  = (const float*)d_in[16];
  float* y = (float*)d_out;

  // workspace layout (72.6 MB total)
  float* xT   = (float*)d_ws;                        // NPIX*128 f32
  float* xp   = xT   + (size_t)NPIX*CCH;             // NPIX*128 f32
  float* offb = xp   + (size_t)NPIX*CCH;             // NPIX*72  f32
  float* mb   = offb + (size_t)NPIX*(GG*PP*2);       // NPIX*36  f32
  u16*  xTb   = (u16*)(mb + (size_t)NPIX*(GG*PP));   // NPIX*128 bf16
  u16*  x1b   = xTb + (size_t)NPIX*CCH;              // NPIX*128 bf16
  u16*  wbuf  = x1b + (size_t)NPIX*CCH;              // (128+112+128)*128 bf16
  u16*  w_inT  = wbuf;
  u16*  w_omT  = w_inT + 128*128;
  u16*  w_outT = w_omT + 112*128;
  u16*  dcnb  = xTb;   // alias: xTb dead after k_proj_mfma

  dim3 trg(SS/32, CCH/32, NN), trb(32, 8);
  k_prep<<<368, 128, 0, stream>>>(w_in, w_off, w_mask, w_out, w_inT, w_omT, w_outT);
  k_tr_in<<<trg, trb, 0, stream>>>(x, xT, xTb);
  k_proj_mfma<<<NPIX/64, 256, 0, stream>>>(xTb, w_inT, b_in, xp);
  k_dwln8<<<NPIX/8, 128, 0, stream>>>(xT, dw_w, dw_b, ln_g, ln_b, x1b);
  k_om_mfma<<<NPIX/64, 256, 0, stream>>>(x1b, w_omT, b_off, b_mask, offb, mb);
  k_dcn8<<<NPIX/8, 256, 0, stream>>>(xp, offb, mb, dcnb);
  k_out_mfma<<<NPIX/64, 256, 0, stream>>>(dcnb, w_outT, b_out,
                                          bn_g, bn_b, bn_mean, bn_var, y);
}